// Round 3
// baseline (429.597 us; speedup 1.0000x reference)
//
#include <hip/hip_runtime.h>
#include <math.h>

#define HH 56
#define WW 56
#define CC 256
#define TT 8
#define HW 3136

// ---------------- K1: attn partial conv2d, channel-split + atomics --------
// grid = bt(32) x hwtile(13) x csplit(4); thread = one output pixel.
__global__ __launch_bounds__(256)
void k1_attn(const float* __restrict__ x, const float* __restrict__ aw,
             float* __restrict__ attn_raw) {
    const int blk  = blockIdx.x;
    const int cs   = blk & 3;
    const int tile = (blk >> 2) % 13;
    const int bt   = blk / 52;
    const int hw   = tile * 256 + threadIdx.x;

    __shared__ float wl[64][9][4];          // 9216 B
    for (int i = threadIdx.x; i < 64 * 9 * 4; i += 256) {
        int cl  = i / 36;
        int rem = i - cl * 36;
        int tap = rem >> 2;
        int o   = rem & 3;
        wl[cl][tap][o] = aw[((size_t)o * CC + cs * 64 + cl) * 9 + tap];
    }
    __syncthreads();

    const bool valid = hw < HW;
    const int row = hw / WW, col = hw % WW;
    int  off[9];
    bool ok[9];
    #pragma unroll
    for (int ki = 0; ki < 3; ++ki)
        #pragma unroll
        for (int kj = 0; kj < 3; ++kj) {
            int r = row + ki - 1, cc = col + kj - 1;
            ok[ki * 3 + kj]  = valid && (unsigned)r < HH && (unsigned)cc < WW;
            off[ki * 3 + kj] = r * WW + cc;
        }

    float acc0 = 0.f, acc1 = 0.f, acc2 = 0.f, acc3 = 0.f;
    const float* xb = x + ((size_t)bt * CC + cs * 64) * HW;
    #pragma unroll 2
    for (int cl = 0; cl < 64; ++cl) {
        const float* xp = xb + (size_t)cl * HW;
        #pragma unroll
        for (int tap = 0; tap < 9; ++tap) {
            float v = ok[tap] ? xp[off[tap]] : 0.f;
            const float4 w = *(const float4*)&wl[cl][tap][0];
            acc0 = fmaf(w.x, v, acc0);
            acc1 = fmaf(w.y, v, acc1);
            acc2 = fmaf(w.z, v, acc2);
            acc3 = fmaf(w.w, v, acc3);
        }
    }
    if (valid) {
        atomicAdd(&attn_raw[((size_t)bt * 4 + 0) * HW + hw], acc0);
        atomicAdd(&attn_raw[((size_t)bt * 4 + 1) * HW + hw], acc1);
        atomicAdd(&attn_raw[((size_t)bt * 4 + 2) * HW + hw], acc2);
        atomicAdd(&attn_raw[((size_t)bt * 4 + 3) * HW + hw], acc3);
    }
}

// ---------------- K1b: attn = sigmoid(relu(raw + bias)) -------------------
__global__ void k1b_act(const float* __restrict__ raw, const float* __restrict__ ab,
                        float* __restrict__ attn) {
    int i = blockIdx.x * 256 + threadIdx.x;
    if (i >= 32 * 4 * HW) return;
    int o = (i / HW) & 3;
    float z = fmaxf(raw[i] + ab[o], 0.f);
    attn[i] = 1.f / (1.f + expf(-z));
}

// ---------------- K2: per-channel BN partial sums of xh = x*attn ----------
__global__ __launch_bounds__(256)
void k2_stats(const float* __restrict__ x, const float* __restrict__ attn,
              float* __restrict__ bn_sum, float* __restrict__ bn_sumsq) {
    const int c  = blockIdx.x & 255;
    const int bt = blockIdx.x >> 8;
    const int head = c >> 6;
    const float4* xp = (const float4*)(x + ((size_t)bt * CC + c) * HW);
    const float4* ap = (const float4*)(attn + ((size_t)bt * 4 + head) * HW);
    float s = 0.f, s2 = 0.f;
    for (int i = threadIdx.x; i < HW / 4; i += 256) {
        float4 xv = xp[i], av = ap[i];
        float v0 = xv.x * av.x, v1 = xv.y * av.y, v2 = xv.z * av.z, v3 = xv.w * av.w;
        s  += v0 + v1 + v2 + v3;
        s2 += v0 * v0 + v1 * v1 + v2 * v2 + v3 * v3;
    }
    #pragma unroll
    for (int off = 32; off > 0; off >>= 1) {
        s  += __shfl_down(s, off);
        s2 += __shfl_down(s2, off);
    }
    __shared__ float red[8];
    const int wave = threadIdx.x >> 6;
    if ((threadIdx.x & 63) == 0) { red[wave * 2] = s; red[wave * 2 + 1] = s2; }
    __syncthreads();
    if (threadIdx.x == 0) {
        atomicAdd(&bn_sum[c],   red[0] + red[2] + red[4] + red[6]);
        atomicAdd(&bn_sumsq[c], red[1] + red[3] + red[5] + red[7]);
    }
}

// ---------------- K3: finalize BN -> per-channel scale/shift --------------
__global__ void k3_final(const float* __restrict__ bn_sum, const float* __restrict__ bn_sumsq,
                         const float* __restrict__ gamma, const float* __restrict__ beta,
                         float* __restrict__ scale, float* __restrict__ shift) {
    int c = threadIdx.x;
    const float invN = 1.f / 100352.f;            // B*T*H*W
    float mean = bn_sum[c] * invN;
    float var  = bn_sumsq[c] * invN - mean * mean;
    float sc   = gamma[c] * rsqrtf(var + 1e-5f);
    scale[c] = sc;
    shift[c] = fmaf(-mean, sc, beta[c]);
}

// ---------------- K4: grouped dilated conv3d, direct-global, no barriers --
// grid = b(4) x hwtile(13) x chunk(32 of 8 ch); thread = one output pixel.
// Weights staged once in LDS, hoisted to regs per channel. xr recomputed
// from x*attn*sc+sh per tap; OOB taps forced to 0 AFTER relu (zero padding
// in xr space). acc[dil][t_out] fully static; 16 atomicAdds at the end.
__global__ __launch_bounds__(256)
void k4_gate(const float* __restrict__ x, const float* __restrict__ attn,
             const float* __restrict__ scale, const float* __restrict__ shift,
             const float* __restrict__ gw0, const float* __restrict__ gw1,
             float* __restrict__ gate_raw) {
    const int blk   = blockIdx.x;
    const int chunk = blk & 31;             // 32 chunks x 8 channels
    const int tile  = (blk >> 5) % 13;
    const int b     = blk / (32 * 13);
    const int g     = chunk >> 4;           // group: ch 0..127 -> 0, 128..255 -> 1
    const int hw    = tile * 256 + threadIdx.x;

    __shared__ float wl[8][2][27];          // 1728 B
    for (int i = threadIdx.x; i < 8 * 2 * 27; i += 256) {
        int cl  = i / 54;
        int rem = i - cl * 54;
        int dil = rem / 27;
        int idx = rem - dil * 27;
        int ci  = (chunk * 8 + cl) & 127;
        const float* src = dil ? gw1 : gw0;
        wl[cl][dil][idx] = src[((size_t)g * 128 + ci) * 27 + idx];
    }
    __syncthreads();

    const bool valid = hw < HW;
    const int row = hw / WW, col = hw % WW;
    int  off[9];
    bool ok[9];
    #pragma unroll
    for (int ki = 0; ki < 3; ++ki)
        #pragma unroll
        for (int kj = 0; kj < 3; ++kj) {
            int r = row + ki - 1, cc = col + kj - 1;
            ok[ki * 3 + kj]  = valid && (unsigned)r < HH && (unsigned)cc < WW;
            off[ki * 3 + kj] = r * WW + cc;
        }

    float acc[2][8];
    #pragma unroll
    for (int d = 0; d < 2; ++d)
        #pragma unroll
        for (int t = 0; t < 8; ++t) acc[d][t] = 0.f;

    for (int cl = 0; cl < 8; ++cl) {
        const int c    = chunk * 8 + cl;
        const int head = c >> 6;
        const float sc = scale[c], sh = shift[c];
        float w0r[27], w1r[27];
        #pragma unroll
        for (int k = 0; k < 27; ++k) { w0r[k] = wl[cl][0][k]; w1r[k] = wl[cl][1][k]; }
        #pragma unroll
        for (int t = 0; t < 8; ++t) {
            const int bti = b * TT + t;
            const float* xp = x    + ((size_t)bti * CC + c)    * HW;
            const float* ap = attn + ((size_t)bti * 4  + head) * HW;
            #pragma unroll
            for (int tap = 0; tap < 9; ++tap) {
                float xv = ok[tap] ? xp[off[tap]] : 0.f;
                float av = ok[tap] ? ap[off[tap]] : 0.f;
                float v  = fmaxf(fmaf(xv * av, sc, sh), 0.f);
                v = ok[tap] ? v : 0.f;      // zero padding in xr space
                #pragma unroll
                for (int kd = 0; kd < 3; ++kd) {
                    constexpr int dummy = 0; (void)dummy;
                    {   // dilation 1: t_out = t + 1 - kd
                        const int to = t + 1 - kd;
                        if (to >= 0 && to < 8)
                            acc[0][to] = fmaf(w0r[kd * 9 + tap], v, acc[0][to]);
                    }
                    {   // dilation 2: t_out = t + 2 - 2*kd
                        const int to = t + 2 - 2 * kd;
                        if (to >= 0 && to < 8)
                            acc[1][to] = fmaf(w1r[kd * 9 + tap], v, acc[1][to]);
                    }
                }
            }
        }
    }
    if (valid) {
        #pragma unroll
        for (int d = 0; d < 2; ++d)
            #pragma unroll
            for (int t = 0; t < 8; ++t)
                atomicAdd(&gate_raw[(((size_t)(d * 4 + b) * 2 + g) * 8 + t) * HW + hw],
                          acc[d][t]);
    }
}

// ---------------- K4b: gate = tanh(raw + bias) ----------------------------
__global__ void k4b_tanh(const float* __restrict__ raw, const float* __restrict__ gb0,
                         const float* __restrict__ gb1, float* __restrict__ gt) {
    int i = blockIdx.x * 256 + threadIdx.x;
    if (i >= 401408) return;
    int d   = i / 200704;
    int rem = i - d * 200704;
    int g   = (rem / 25088) & 1;        // 8*3136 per (g) slab
    float bias = (d == 0) ? gb0[g] : gb1[g];
    gt[i] = tanhf(raw[i] + bias);
}

// ---------------- K5: fuse + shuffle + alpha-combine ----------------------
// thread owns (b, c_out, hw) across all 8 t: x read exactly once.
__global__ __launch_bounds__(256)
void k5_fuse(const float* __restrict__ x, const float* __restrict__ attn,
             const float* __restrict__ scale, const float* __restrict__ shift,
             const float* __restrict__ gt, const float* __restrict__ alpha,
             float* __restrict__ out) {
    const int blk  = blockIdx.x;
    const int tile = blk % 13;
    const int c    = (blk / 13) & 255;
    const int b    = blk / (13 * 256);
    const int hw   = tile * 256 + threadIdx.x;
    if (hw >= HW) return;
    const int clo  = c & 127;
    const int cs   = (c & 128) | ((clo & 1) << 6) | (clo >> 1);  // inverse shuffle
    const int g    = c >> 7;
    const int head = cs >> 6;
    const float sc = scale[cs], sh = shift[cs];
    float xr[8], G0[8], G1[8];
    #pragma unroll
    for (int t = 0; t < 8; ++t) {
        const int bti = b * 8 + t;
        float xv = x[((size_t)bti * CC + cs) * HW + hw];
        float av = attn[((size_t)bti * 4 + head) * HW + hw];
        xr[t] = fmaxf(fmaf(xv * av, sc, sh), 0.f);
        G0[t] = gt[(((size_t)(0 * 4 + b) * 2 + g) * 8 + t) * HW + hw];
        G1[t] = gt[(((size_t)(1 * 4 + b) * 2 + g) * 8 + t) * HW + hw];
    }
    const float a0 = alpha[0], a1 = alpha[1];
    #pragma unroll
    for (int t = 0; t < 8; ++t) {
        float v0, v1;
        if (g == 0) {   // shift-left group: neighbor at t+d
            v0 = xr[t] * (1.f - G0[t]) + (t + 1 < 8 ? G0[t + 1] * xr[t + 1] : 0.f);
            v1 = xr[t] * (1.f - G1[t]) + (t + 2 < 8 ? G1[t + 2] * xr[t + 2] : 0.f);
        } else {        // shift-right group: neighbor at t-d
            v0 = xr[t] * (1.f - G0[t]) + (t - 1 >= 0 ? G0[t - 1] * xr[t - 1] : 0.f);
            v1 = xr[t] * (1.f - G1[t]) + (t - 2 >= 0 ? G1[t - 2] * xr[t - 2] : 0.f);
        }
        out[((size_t)(b * 8 + t) * CC + c) * HW + hw] = fmaf(a0, v0, a1 * v1);
    }
}

extern "C" void kernel_launch(void* const* d_in, const int* in_sizes, int n_in,
                              void* d_out, int out_size, void* d_ws, size_t ws_size,
                              hipStream_t stream) {
    const float* x     = (const float*)d_in[0];
    const float* aw    = (const float*)d_in[1];
    const float* ab    = (const float*)d_in[2];
    const float* gamma = (const float*)d_in[3];
    const float* beta  = (const float*)d_in[4];
    const float* gw0   = (const float*)d_in[5];
    const float* gb0   = (const float*)d_in[6];
    const float* gw1   = (const float*)d_in[7];
    const float* gb1   = (const float*)d_in[8];
    const float* alpha = (const float*)d_in[9];
    float* out = (float*)d_out;
    float* ws  = (float*)d_ws;

    // ws layout (floats):
    //   [gate_raw 401408 | attn_raw/gate_t 401408 | bn_sum 256 | bn_sumsq 256 |
    //    attn 401408 | scale 256 | shift 256]
    float* gate_raw = ws;
    float* attn_raw = ws + 401408;
    float* gate_t   = attn_raw;             // alias (timeline-disjoint)
    float* bn_sum   = ws + 802816;
    float* bn_sumsq = ws + 803072;
    float* attn     = ws + 803328;
    float* scale    = ws + 1204736;
    float* shift    = ws + 1204992;

    // zero all atomic-accumulated regions in one memset (contiguous prefix)
    hipMemsetAsync(ws, 0, (size_t)(401408 + 401408 + 512) * sizeof(float), stream);

    k1_attn <<<dim3(1664),  dim3(256), 0, stream>>>(x, aw, attn_raw);
    k1b_act <<<dim3(1568),  dim3(256), 0, stream>>>(attn_raw, ab, attn);
    k2_stats<<<dim3(8192),  dim3(256), 0, stream>>>(x, attn, bn_sum, bn_sumsq);
    k3_final<<<dim3(1),     dim3(256), 0, stream>>>(bn_sum, bn_sumsq, gamma, beta, scale, shift);
    k4_gate <<<dim3(1664),  dim3(256), 0, stream>>>(x, attn, scale, shift, gw0, gw1, gate_raw);
    k4b_tanh<<<dim3(1568),  dim3(256), 0, stream>>>(gate_raw, gb0, gb1, gate_t);
    k5_fuse <<<dim3(13312), dim3(256), 0, stream>>>(x, attn, scale, shift, gate_t, alpha, out);
}

// Round 4
// 244.441 us; speedup vs baseline: 1.7575x; 1.7575x over previous
//
#include <hip/hip_runtime.h>
#include <math.h>

#define HH 56
#define WW 56
#define CC 256
#define TT 8
#define HW 3136

// ---------------- K1: attn partial conv2d, channel-split + atomics --------
// grid = bt(32) x hwtile(13) x csplit(4); thread = one output pixel.
__global__ __launch_bounds__(256)
void k1_attn(const float* __restrict__ x, const float* __restrict__ aw,
             float* __restrict__ attn_raw) {
    const int blk  = blockIdx.x;
    const int cs   = blk & 3;
    const int tile = (blk >> 2) % 13;
    const int bt   = blk / 52;
    const int hw   = tile * 256 + threadIdx.x;

    __shared__ float wl[64][9][4];          // 9216 B
    for (int i = threadIdx.x; i < 64 * 9 * 4; i += 256) {
        int cl  = i / 36;
        int rem = i - cl * 36;
        int tap = rem >> 2;
        int o   = rem & 3;
        wl[cl][tap][o] = aw[((size_t)o * CC + cs * 64 + cl) * 9 + tap];
    }
    __syncthreads();

    const bool valid = hw < HW;
    const int row = hw / WW, col = hw % WW;
    int  off[9];
    bool ok[9];
    #pragma unroll
    for (int ki = 0; ki < 3; ++ki)
        #pragma unroll
        for (int kj = 0; kj < 3; ++kj) {
            int r = row + ki - 1, cc = col + kj - 1;
            ok[ki * 3 + kj]  = valid && (unsigned)r < HH && (unsigned)cc < WW;
            off[ki * 3 + kj] = r * WW + cc;
        }

    float acc0 = 0.f, acc1 = 0.f, acc2 = 0.f, acc3 = 0.f;
    const float* xb = x + ((size_t)bt * CC + cs * 64) * HW;
    #pragma unroll 2
    for (int cl = 0; cl < 64; ++cl) {
        const float* xp = xb + (size_t)cl * HW;
        #pragma unroll
        for (int tap = 0; tap < 9; ++tap) {
            float v = ok[tap] ? xp[off[tap]] : 0.f;
            const float4 w = *(const float4*)&wl[cl][tap][0];
            acc0 = fmaf(w.x, v, acc0);
            acc1 = fmaf(w.y, v, acc1);
            acc2 = fmaf(w.z, v, acc2);
            acc3 = fmaf(w.w, v, acc3);
        }
    }
    if (valid) {
        atomicAdd(&attn_raw[((size_t)bt * 4 + 0) * HW + hw], acc0);
        atomicAdd(&attn_raw[((size_t)bt * 4 + 1) * HW + hw], acc1);
        atomicAdd(&attn_raw[((size_t)bt * 4 + 2) * HW + hw], acc2);
        atomicAdd(&attn_raw[((size_t)bt * 4 + 3) * HW + hw], acc3);
    }
}

// ---------------- K1b: attn = sigmoid(relu(raw + bias)) -------------------
__global__ void k1b_act(const float* __restrict__ raw, const float* __restrict__ ab,
                        float* __restrict__ attn) {
    int i = blockIdx.x * 256 + threadIdx.x;
    if (i >= 32 * 4 * HW) return;
    int o = (i / HW) & 3;
    float z = fmaxf(raw[i] + ab[o], 0.f);
    attn[i] = 1.f / (1.f + expf(-z));
}

// ---------------- K2: per-channel BN partial sums of xh = x*attn ----------
__global__ __launch_bounds__(256)
void k2_stats(const float* __restrict__ x, const float* __restrict__ attn,
              float* __restrict__ bn_sum, float* __restrict__ bn_sumsq) {
    const int c  = blockIdx.x & 255;
    const int bt = blockIdx.x >> 8;
    const int head = c >> 6;
    const float4* xp = (const float4*)(x + ((size_t)bt * CC + c) * HW);
    const float4* ap = (const float4*)(attn + ((size_t)bt * 4 + head) * HW);
    float s = 0.f, s2 = 0.f;
    for (int i = threadIdx.x; i < HW / 4; i += 256) {
        float4 xv = xp[i], av = ap[i];
        float v0 = xv.x * av.x, v1 = xv.y * av.y, v2 = xv.z * av.z, v3 = xv.w * av.w;
        s  += v0 + v1 + v2 + v3;
        s2 += v0 * v0 + v1 * v1 + v2 * v2 + v3 * v3;
    }
    #pragma unroll
    for (int off = 32; off > 0; off >>= 1) {
        s  += __shfl_down(s, off);
        s2 += __shfl_down(s2, off);
    }
    __shared__ float red[8];
    const int wave = threadIdx.x >> 6;
    if ((threadIdx.x & 63) == 0) { red[wave * 2] = s; red[wave * 2 + 1] = s2; }
    __syncthreads();
    if (threadIdx.x == 0) {
        atomicAdd(&bn_sum[c],   red[0] + red[2] + red[4] + red[6]);
        atomicAdd(&bn_sumsq[c], red[1] + red[3] + red[5] + red[7]);
    }
}

// ---------------- K3: finalize BN -> per-channel scale/shift --------------
__global__ void k3_final(const float* __restrict__ bn_sum, const float* __restrict__ bn_sumsq,
                         const float* __restrict__ gamma, const float* __restrict__ beta,
                         float* __restrict__ scale, float* __restrict__ shift) {
    int c = threadIdx.x;
    const float invN = 1.f / 100352.f;            // B*T*H*W
    float mean = bn_sum[c] * invN;
    float var  = bn_sumsq[c] * invN - mean * mean;
    float sc   = gamma[c] * rsqrtf(var + 1e-5f);
    scale[c] = sc;
    shift[c] = fmaf(-mean, sc, beta[c]);
}

// ---------------- K4: grouped dilated conv3d, LDS-staged, double-buffered -
// block = (b, 4-row h-tile, 8-ch chunk), 1792 blocks. Per channel: prefetch
// next channel's 11 x-values into regs, compute current from LDS, write
// prefetched (transformed to xr) into the other buffer, ONE barrier.
// attn values are channel-invariant within the chunk -> loaded once to regs.
// OOB halo positions zeroed once in both buffers (zero padding in xr space).
__global__ __launch_bounds__(256)
void k4_gate(const float* __restrict__ x, const float* __restrict__ attn,
             const float* __restrict__ scale, const float* __restrict__ shift,
             const float* __restrict__ gw0, const float* __restrict__ gw1,
             float* __restrict__ gate_raw) {
    const int blk   = blockIdx.x;
    const int chunk = blk & 31;             // 32 chunks x 8 channels
    const int ht    = (blk >> 5) % 14;
    const int b     = blk / (32 * 14);
    const int h0    = ht * 4;
    const int g     = chunk >> 4;           // group: ch 0..127 -> 0, else 1
    const int head  = chunk >> 3;           // 8-ch chunk sits inside one head
    __shared__ float tile[2][TT * 6 * 58];  // 22272 B
    float* tf = &tile[0][0];
    const int tid = threadIdx.x;

    // per-thread staging descriptors (channel-independent), elems 2784
    int   soff[11];
    int   goff[11];      // offset within x for this (b,t,gh,gw), + c*HW later
    float av[11];        // attn value (same for all 8 channels of the chunk)
    bool  vld[11];
    #pragma unroll
    for (int k = 0; k < 11; ++k) {
        int idx = tid + k * 256;
        bool in = idx < TT * 6 * 58;
        int t   = idx / 348;
        int rem = idx - t * 348;
        int r   = rem / 58;
        int col = rem - r * 58;
        int gh = h0 + r - 1, gw = col - 1;
        bool v = in && (unsigned)gh < HH && (unsigned)gw < WW;
        vld[k]  = v;
        soff[k] = idx;                       // layout [t][r][col] == flat idx
        goff[k] = ((b * 8 + t) * CC) * HW + gh * WW + gw;
        av[k]   = v ? attn[((size_t)(b * 8 + t) * 4 + head) * HW + gh * WW + gw] : 0.f;
        if (in && !v) { tf[idx] = 0.f; tf[2784 + idx] = 0.f; }   // zero halo once
    }

    // stage channel 0 into buffer 0
    {
        const int c0 = chunk * 8;
        const float sc = scale[c0], sh = shift[c0];
        #pragma unroll
        for (int k = 0; k < 11; ++k)
            if (vld[k]) {
                float xv = x[(size_t)goff[k] + (size_t)c0 * HW];
                tf[soff[k]] = fmaxf(fmaf(xv * av[k], sc, sh), 0.f);
            }
    }
    __syncthreads();

    const int wc = tid % WW;
    const int hr = tid / WW;
    const bool active = tid < 4 * WW;
    float acc[2][8];
    #pragma unroll
    for (int d = 0; d < 2; ++d)
        #pragma unroll
        for (int t = 0; t < 8; ++t) acc[d][t] = 0.f;

    for (int cl = 0; cl < 8; ++cl) {
        const int c = chunk * 8 + cl;
        // prefetch next channel into regs (latency hidden under compute)
        float xv[11];
        if (cl < 7) {
            #pragma unroll
            for (int k = 0; k < 11; ++k)
                xv[k] = vld[k] ? x[(size_t)goff[k] + (size_t)(c + 1) * HW] : 0.f;
        }
        // compute current channel from LDS buffer (cl&1)
        if (active) {
            const float* buf = tf + (cl & 1) * 2784;
            const int ci = c & 127;
            const float* wp0 = gw0 + ((size_t)g * 128 + ci) * 27;  // dil 1
            const float* wp1 = gw1 + ((size_t)g * 128 + ci) * 27;  // dil 2
            #pragma unroll
            for (int t = 0; t < 8; ++t) {
                float v[9];
                #pragma unroll
                for (int ki = 0; ki < 3; ++ki)
                    #pragma unroll
                    for (int kj = 0; kj < 3; ++kj)
                        v[ki * 3 + kj] = buf[t * 348 + (hr + ki) * 58 + wc + kj];
                #pragma unroll
                for (int kd = 0; kd < 3; ++kd) {
                    {   // dilation 1: t_out = t + 1 - kd
                        const int to = t + 1 - kd;
                        if (to >= 0 && to < 8) {
                            float s = 0.f;
                            #pragma unroll
                            for (int k = 0; k < 9; ++k) s = fmaf(wp0[kd * 9 + k], v[k], s);
                            acc[0][to] += s;
                        }
                    }
                    {   // dilation 2: t_out = t + 2 - 2*kd
                        const int to = t + 2 - 2 * kd;
                        if (to >= 0 && to < 8) {
                            float s = 0.f;
                            #pragma unroll
                            for (int k = 0; k < 9; ++k) s = fmaf(wp1[kd * 9 + k], v[k], s);
                            acc[1][to] += s;
                        }
                    }
                }
            }
        }
        // write prefetched channel (transformed to xr) into other buffer
        if (cl < 7) {
            const float scn = scale[c + 1], shn = shift[c + 1];
            float* bufn = tf + ((cl + 1) & 1) * 2784;
            #pragma unroll
            for (int k = 0; k < 11; ++k)
                if (vld[k])
                    bufn[soff[k]] = fmaxf(fmaf(xv[k] * av[k], scn, shn), 0.f);
        }
        __syncthreads();
    }

    if (active) {
        const int hw = (h0 + hr) * WW + wc;
        #pragma unroll
        for (int d = 0; d < 2; ++d)
            #pragma unroll
            for (int t = 0; t < 8; ++t)
                atomicAdd(&gate_raw[(((size_t)(d * 4 + b) * 2 + g) * 8 + t) * HW + hw],
                          acc[d][t]);
    }
}

// ---------------- K4b: gate = tanh(raw + bias) ----------------------------
__global__ void k4b_tanh(const float* __restrict__ raw, const float* __restrict__ gb0,
                         const float* __restrict__ gb1, float* __restrict__ gt) {
    int i = blockIdx.x * 256 + threadIdx.x;
    if (i >= 401408) return;
    int d   = i / 200704;
    int rem = i - d * 200704;
    int g   = (rem / 25088) & 1;        // 8*3136 per (g) slab
    float bias = (d == 0) ? gb0[g] : gb1[g];
    gt[i] = tanhf(raw[i] + bias);
}

// ---------------- K5: fuse + shuffle + alpha-combine ----------------------
// thread owns (b, c_out, hw) across all 8 t: x read exactly once.
__global__ __launch_bounds__(256)
void k5_fuse(const float* __restrict__ x, const float* __restrict__ attn,
             const float* __restrict__ scale, const float* __restrict__ shift,
             const float* __restrict__ gt, const float* __restrict__ alpha,
             float* __restrict__ out) {
    const int blk  = blockIdx.x;
    const int tile = blk % 13;
    const int c    = (blk / 13) & 255;
    const int b    = blk / (13 * 256);
    const int hw   = tile * 256 + threadIdx.x;
    if (hw >= HW) return;
    const int clo  = c & 127;
    const int cs   = (c & 128) | ((clo & 1) << 6) | (clo >> 1);  // inverse shuffle
    const int g    = c >> 7;
    const int head = cs >> 6;
    const float sc = scale[cs], sh = shift[cs];
    float xr[8], G0[8], G1[8];
    #pragma unroll
    for (int t = 0; t < 8; ++t) {
        const int bti = b * 8 + t;
        float xv = x[((size_t)bti * CC + cs) * HW + hw];
        float av = attn[((size_t)bti * 4 + head) * HW + hw];
        xr[t] = fmaxf(fmaf(xv * av, sc, sh), 0.f);
        G0[t] = gt[(((size_t)(0 * 4 + b) * 2 + g) * 8 + t) * HW + hw];
        G1[t] = gt[(((size_t)(1 * 4 + b) * 2 + g) * 8 + t) * HW + hw];
    }
    const float a0 = alpha[0], a1 = alpha[1];
    #pragma unroll
    for (int t = 0; t < 8; ++t) {
        float v0, v1;
        if (g == 0) {   // shift-left group: neighbor at t+d
            v0 = xr[t] * (1.f - G0[t]) + (t + 1 < 8 ? G0[t + 1] * xr[t + 1] : 0.f);
            v1 = xr[t] * (1.f - G1[t]) + (t + 2 < 8 ? G1[t + 2] * xr[t + 2] : 0.f);
        } else {        // shift-right group: neighbor at t-d
            v0 = xr[t] * (1.f - G0[t]) + (t - 1 >= 0 ? G0[t - 1] * xr[t - 1] : 0.f);
            v1 = xr[t] * (1.f - G1[t]) + (t - 2 >= 0 ? G1[t - 2] * xr[t - 2] : 0.f);
        }
        out[((size_t)(b * 8 + t) * CC + c) * HW + hw] = fmaf(a0, v0, a1 * v1);
    }
}

extern "C" void kernel_launch(void* const* d_in, const int* in_sizes, int n_in,
                              void* d_out, int out_size, void* d_ws, size_t ws_size,
                              hipStream_t stream) {
    const float* x     = (const float*)d_in[0];
    const float* aw    = (const float*)d_in[1];
    const float* ab    = (const float*)d_in[2];
    const float* gamma = (const float*)d_in[3];
    const float* beta  = (const float*)d_in[4];
    const float* gw0   = (const float*)d_in[5];
    const float* gb0   = (const float*)d_in[6];
    const float* gw1   = (const float*)d_in[7];
    const float* gb1   = (const float*)d_in[8];
    const float* alpha = (const float*)d_in[9];
    float* out = (float*)d_out;
    float* ws  = (float*)d_ws;

    // ws layout (floats):
    //   [gate_raw 401408 | attn_raw/gate_t 401408 | bn_sum 256 | bn_sumsq 256 |
    //    attn 401408 | scale 256 | shift 256]
    float* gate_raw = ws;
    float* attn_raw = ws + 401408;
    float* gate_t   = attn_raw;             // alias (timeline-disjoint)
    float* bn_sum   = ws + 802816;
    float* bn_sumsq = ws + 803072;
    float* attn     = ws + 803328;
    float* scale    = ws + 1204736;
    float* shift    = ws + 1204992;

    // zero all atomic-accumulated regions in one memset (contiguous prefix)
    hipMemsetAsync(ws, 0, (size_t)(401408 + 401408 + 512) * sizeof(float), stream);

    k1_attn <<<dim3(1664),  dim3(256), 0, stream>>>(x, aw, attn_raw);
    k1b_act <<<dim3(1568),  dim3(256), 0, stream>>>(attn_raw, ab, attn);
    k2_stats<<<dim3(8192),  dim3(256), 0, stream>>>(x, attn, bn_sum, bn_sumsq);
    k3_final<<<dim3(1),     dim3(256), 0, stream>>>(bn_sum, bn_sumsq, gamma, beta, scale, shift);
    k4_gate <<<dim3(1792),  dim3(256), 0, stream>>>(x, attn, scale, shift, gw0, gw1, gate_raw);
    k4b_tanh<<<dim3(1568),  dim3(256), 0, stream>>>(gate_raw, gb0, gb1, gate_t);
    k5_fuse <<<dim3(13312), dim3(256), 0, stream>>>(x, attn, scale, shift, gate_t, alpha, out);
}

// Round 5
// 229.347 us; speedup vs baseline: 1.8731x; 1.0658x over previous
//
#include <hip/hip_runtime.h>
#include <math.h>

#define HH 56
#define WW 56
#define CC 256
#define TT 8
#define HW 3136

// ---------------- K1: attn partial conv2d, row-per-wave, shuffle taps -----
// grid = bt(32) x rowband(14 of 4 rows) x csplit(4 of 64 ch) = 1792 blocks.
// Wave owns one output row; lane = column. Per channel: 3 vertical loads
// (row-1,row,row+1 at own column), horizontal taps via __shfl_up/down.
// Weights are wave-uniform -> scalar loads. No LDS, no barriers.
__global__ __launch_bounds__(256)
void k1_attn(const float* __restrict__ x, const float* __restrict__ aw,
             float* __restrict__ attn_raw) {
    const int blk  = blockIdx.x;
    const int cs   = blk & 3;
    const int ht   = (blk >> 2) % 14;
    const int bt   = blk / 56;
    const int wave = threadIdx.x >> 6;
    const int lane = threadIdx.x & 63;
    const int row  = ht * 4 + wave;
    const int col  = lane;
    const bool live = col < WW;
    const bool okm = row > 0, okp = row < HH - 1;
    const int base = row * WW + col;
    const int offm = okm ? base - WW : base;   // clamped (safe) address
    const int offp = okp ? base + WW : base;
    const float* xb = x + ((size_t)bt * CC + cs * 64) * HW;

    float a0 = 0.f, a1 = 0.f, a2 = 0.f, a3 = 0.f;
    #pragma unroll 4
    for (int cl = 0; cl < 64; ++cl) {
        const float* xp = xb + (size_t)cl * HW;
        float vm = (live && okm) ? xp[offm] : 0.f;
        float vc = live ? xp[base] : 0.f;
        float vp = (live && okp) ? xp[offp] : 0.f;
        // horizontal neighbors via cross-lane shuffle (lanes>=56 hold 0)
        float vml = __shfl_up(vm, 1), vcl = __shfl_up(vc, 1), vpl = __shfl_up(vp, 1);
        if (lane == 0) { vml = 0.f; vcl = 0.f; vpl = 0.f; }
        float vmr = __shfl_down(vm, 1), vcr = __shfl_down(vc, 1), vpr = __shfl_down(vp, 1);

        const int c = cs * 64 + cl;
        const float* w0 = aw + ((size_t)0 * CC + c) * 9;   // uniform -> s_load
        const float* w1 = aw + ((size_t)1 * CC + c) * 9;
        const float* w2 = aw + ((size_t)2 * CC + c) * 9;
        const float* w3 = aw + ((size_t)3 * CC + c) * 9;

        a0 = fmaf(w0[0], vml, a0); a0 = fmaf(w0[1], vm, a0); a0 = fmaf(w0[2], vmr, a0);
        a0 = fmaf(w0[3], vcl, a0); a0 = fmaf(w0[4], vc, a0); a0 = fmaf(w0[5], vcr, a0);
        a0 = fmaf(w0[6], vpl, a0); a0 = fmaf(w0[7], vp, a0); a0 = fmaf(w0[8], vpr, a0);

        a1 = fmaf(w1[0], vml, a1); a1 = fmaf(w1[1], vm, a1); a1 = fmaf(w1[2], vmr, a1);
        a1 = fmaf(w1[3], vcl, a1); a1 = fmaf(w1[4], vc, a1); a1 = fmaf(w1[5], vcr, a1);
        a1 = fmaf(w1[6], vpl, a1); a1 = fmaf(w1[7], vp, a1); a1 = fmaf(w1[8], vpr, a1);

        a2 = fmaf(w2[0], vml, a2); a2 = fmaf(w2[1], vm, a2); a2 = fmaf(w2[2], vmr, a2);
        a2 = fmaf(w2[3], vcl, a2); a2 = fmaf(w2[4], vc, a2); a2 = fmaf(w2[5], vcr, a2);
        a2 = fmaf(w2[6], vpl, a2); a2 = fmaf(w2[7], vp, a2); a2 = fmaf(w2[8], vpr, a2);

        a3 = fmaf(w3[0], vml, a3); a3 = fmaf(w3[1], vm, a3); a3 = fmaf(w3[2], vmr, a3);
        a3 = fmaf(w3[3], vcl, a3); a3 = fmaf(w3[4], vc, a3); a3 = fmaf(w3[5], vcr, a3);
        a3 = fmaf(w3[6], vpl, a3); a3 = fmaf(w3[7], vp, a3); a3 = fmaf(w3[8], vpr, a3);
    }
    if (live) {
        atomicAdd(&attn_raw[((size_t)bt * 4 + 0) * HW + base], a0);
        atomicAdd(&attn_raw[((size_t)bt * 4 + 1) * HW + base], a1);
        atomicAdd(&attn_raw[((size_t)bt * 4 + 2) * HW + base], a2);
        atomicAdd(&attn_raw[((size_t)bt * 4 + 3) * HW + base], a3);
    }
}

// ---------------- K1b: attn = sigmoid(relu(raw + bias)) -------------------
__global__ void k1b_act(const float* __restrict__ raw, const float* __restrict__ ab,
                        float* __restrict__ attn) {
    int i = blockIdx.x * 256 + threadIdx.x;
    if (i >= 32 * 4 * HW) return;
    int o = (i / HW) & 3;
    float z = fmaxf(raw[i] + ab[o], 0.f);
    attn[i] = 1.f / (1.f + expf(-z));
}

// ---------------- K2: per-channel BN partial sums of xh = x*attn ----------
__global__ __launch_bounds__(256)
void k2_stats(const float* __restrict__ x, const float* __restrict__ attn,
              float* __restrict__ bn_sum, float* __restrict__ bn_sumsq) {
    const int c  = blockIdx.x & 255;
    const int bt = blockIdx.x >> 8;
    const int head = c >> 6;
    const float4* xp = (const float4*)(x + ((size_t)bt * CC + c) * HW);
    const float4* ap = (const float4*)(attn + ((size_t)bt * 4 + head) * HW);
    float s = 0.f, s2 = 0.f;
    for (int i = threadIdx.x; i < HW / 4; i += 256) {
        float4 xv = xp[i], av = ap[i];
        float v0 = xv.x * av.x, v1 = xv.y * av.y, v2 = xv.z * av.z, v3 = xv.w * av.w;
        s  += v0 + v1 + v2 + v3;
        s2 += v0 * v0 + v1 * v1 + v2 * v2 + v3 * v3;
    }
    #pragma unroll
    for (int off = 32; off > 0; off >>= 1) {
        s  += __shfl_down(s, off);
        s2 += __shfl_down(s2, off);
    }
    __shared__ float red[8];
    const int wave = threadIdx.x >> 6;
    if ((threadIdx.x & 63) == 0) { red[wave * 2] = s; red[wave * 2 + 1] = s2; }
    __syncthreads();
    if (threadIdx.x == 0) {
        atomicAdd(&bn_sum[c],   red[0] + red[2] + red[4] + red[6]);
        atomicAdd(&bn_sumsq[c], red[1] + red[3] + red[5] + red[7]);
    }
}

// ---------------- K3: finalize BN -> per-channel scale/shift --------------
__global__ void k3_final(const float* __restrict__ bn_sum, const float* __restrict__ bn_sumsq,
                         const float* __restrict__ gamma, const float* __restrict__ beta,
                         float* __restrict__ scale, float* __restrict__ shift) {
    int c = threadIdx.x;
    const float invN = 1.f / 100352.f;            // B*T*H*W
    float mean = bn_sum[c] * invN;
    float var  = bn_sumsq[c] * invN - mean * mean;
    float sc   = gamma[c] * rsqrtf(var + 1e-5f);
    scale[c] = sc;
    shift[c] = fmaf(-mean, sc, beta[c]);
}

// ---------------- K4: grouped dilated conv3d, LDS-staged, double-buffered -
__global__ __launch_bounds__(256)
void k4_gate(const float* __restrict__ x, const float* __restrict__ attn,
             const float* __restrict__ scale, const float* __restrict__ shift,
             const float* __restrict__ gw0, const float* __restrict__ gw1,
             float* __restrict__ gate_raw) {
    const int blk   = blockIdx.x;
    const int chunk = blk & 31;             // 32 chunks x 8 channels
    const int ht    = (blk >> 5) % 14;
    const int b     = blk / (32 * 14);
    const int h0    = ht * 4;
    const int g     = chunk >> 4;           // group: ch 0..127 -> 0, else 1
    const int head  = chunk >> 3;           // 8-ch chunk sits inside one head
    __shared__ float tile[2][TT * 6 * 58];  // 22272 B
    float* tf = &tile[0][0];
    const int tid = threadIdx.x;

    // per-thread staging descriptors (channel-independent), elems 2784
    int   soff[11];
    int   goff[11];
    float av[11];
    bool  vld[11];
    #pragma unroll
    for (int k = 0; k < 11; ++k) {
        int idx = tid + k * 256;
        bool in = idx < TT * 6 * 58;
        int t   = idx / 348;
        int rem = idx - t * 348;
        int r   = rem / 58;
        int col = rem - r * 58;
        int gh = h0 + r - 1, gw = col - 1;
        bool v = in && (unsigned)gh < HH && (unsigned)gw < WW;
        vld[k]  = v;
        soff[k] = idx;
        goff[k] = ((b * 8 + t) * CC) * HW + gh * WW + gw;
        av[k]   = v ? attn[((size_t)(b * 8 + t) * 4 + head) * HW + gh * WW + gw] : 0.f;
        if (in && !v) { tf[idx] = 0.f; tf[2784 + idx] = 0.f; }
    }

    {
        const int c0 = chunk * 8;
        const float sc = scale[c0], sh = shift[c0];
        #pragma unroll
        for (int k = 0; k < 11; ++k)
            if (vld[k]) {
                float xv = x[(size_t)goff[k] + (size_t)c0 * HW];
                tf[soff[k]] = fmaxf(fmaf(xv * av[k], sc, sh), 0.f);
            }
    }
    __syncthreads();

    const int wc = tid % WW;
    const int hr = tid / WW;
    const bool active = tid < 4 * WW;
    float acc[2][8];
    #pragma unroll
    for (int d = 0; d < 2; ++d)
        #pragma unroll
        for (int t = 0; t < 8; ++t) acc[d][t] = 0.f;

    for (int cl = 0; cl < 8; ++cl) {
        const int c = chunk * 8 + cl;
        float xv[11];
        if (cl < 7) {
            #pragma unroll
            for (int k = 0; k < 11; ++k)
                xv[k] = vld[k] ? x[(size_t)goff[k] + (size_t)(c + 1) * HW] : 0.f;
        }
        if (active) {
            const float* buf = tf + (cl & 1) * 2784;
            const int ci = c & 127;
            const float* wp0 = gw0 + ((size_t)g * 128 + ci) * 27;
            const float* wp1 = gw1 + ((size_t)g * 128 + ci) * 27;
            #pragma unroll
            for (int t = 0; t < 8; ++t) {
                float v[9];
                #pragma unroll
                for (int ki = 0; ki < 3; ++ki)
                    #pragma unroll
                    for (int kj = 0; kj < 3; ++kj)
                        v[ki * 3 + kj] = buf[t * 348 + (hr + ki) * 58 + wc + kj];
                #pragma unroll
                for (int kd = 0; kd < 3; ++kd) {
                    {
                        const int to = t + 1 - kd;
                        if (to >= 0 && to < 8) {
                            float s = 0.f;
                            #pragma unroll
                            for (int k = 0; k < 9; ++k) s = fmaf(wp0[kd * 9 + k], v[k], s);
                            acc[0][to] += s;
                        }
                    }
                    {
                        const int to = t + 2 - 2 * kd;
                        if (to >= 0 && to < 8) {
                            float s = 0.f;
                            #pragma unroll
                            for (int k = 0; k < 9; ++k) s = fmaf(wp1[kd * 9 + k], v[k], s);
                            acc[1][to] += s;
                        }
                    }
                }
            }
        }
        if (cl < 7) {
            const float scn = scale[c + 1], shn = shift[c + 1];
            float* bufn = tf + ((cl + 1) & 1) * 2784;
            #pragma unroll
            for (int k = 0; k < 11; ++k)
                if (vld[k])
                    bufn[soff[k]] = fmaxf(fmaf(xv[k] * av[k], scn, shn), 0.f);
        }
        __syncthreads();
    }

    if (active) {
        const int hw = (h0 + hr) * WW + wc;
        #pragma unroll
        for (int d = 0; d < 2; ++d)
            #pragma unroll
            for (int t = 0; t < 8; ++t)
                atomicAdd(&gate_raw[(((size_t)(d * 4 + b) * 2 + g) * 8 + t) * HW + hw],
                          acc[d][t]);
    }
}

// ---------------- K4b: gate = tanh(raw + bias) ----------------------------
__global__ void k4b_tanh(const float* __restrict__ raw, const float* __restrict__ gb0,
                         const float* __restrict__ gb1, float* __restrict__ gt) {
    int i = blockIdx.x * 256 + threadIdx.x;
    if (i >= 401408) return;
    int d   = i / 200704;
    int rem = i - d * 200704;
    int g   = (rem / 25088) & 1;
    float bias = (d == 0) ? gb0[g] : gb1[g];
    gt[i] = tanhf(raw[i] + bias);
}

// ---------------- K5: fuse + shuffle + alpha-combine ----------------------
__global__ __launch_bounds__(256)
void k5_fuse(const float* __restrict__ x, const float* __restrict__ attn,
             const float* __restrict__ scale, const float* __restrict__ shift,
             const float* __restrict__ gt, const float* __restrict__ alpha,
             float* __restrict__ out) {
    const int blk  = blockIdx.x;
    const int tile = blk % 13;
    const int c    = (blk / 13) & 255;
    const int b    = blk / (13 * 256);
    const int hw   = tile * 256 + threadIdx.x;
    if (hw >= HW) return;
    const int clo  = c & 127;
    const int cs   = (c & 128) | ((clo & 1) << 6) | (clo >> 1);  // inverse shuffle
    const int g    = c >> 7;
    const int head = cs >> 6;
    const float sc = scale[cs], sh = shift[cs];
    float xr[8], G0[8], G1[8];
    #pragma unroll
    for (int t = 0; t < 8; ++t) {
        const int bti = b * 8 + t;
        float xv = x[((size_t)bti * CC + cs) * HW + hw];
        float av = attn[((size_t)bti * 4 + head) * HW + hw];
        xr[t] = fmaxf(fmaf(xv * av, sc, sh), 0.f);
        G0[t] = gt[(((size_t)(0 * 4 + b) * 2 + g) * 8 + t) * HW + hw];
        G1[t] = gt[(((size_t)(1 * 4 + b) * 2 + g) * 8 + t) * HW + hw];
    }
    const float a0 = alpha[0], a1 = alpha[1];
    #pragma unroll
    for (int t = 0; t < 8; ++t) {
        float v0, v1;
        if (g == 0) {
            v0 = xr[t] * (1.f - G0[t]) + (t + 1 < 8 ? G0[t + 1] * xr[t + 1] : 0.f);
            v1 = xr[t] * (1.f - G1[t]) + (t + 2 < 8 ? G1[t + 2] * xr[t + 2] : 0.f);
        } else {
            v0 = xr[t] * (1.f - G0[t]) + (t - 1 >= 0 ? G0[t - 1] * xr[t - 1] : 0.f);
            v1 = xr[t] * (1.f - G1[t]) + (t - 2 >= 0 ? G1[t - 2] * xr[t - 2] : 0.f);
        }
        out[((size_t)(b * 8 + t) * CC + c) * HW + hw] = fmaf(a0, v0, a1 * v1);
    }
}

extern "C" void kernel_launch(void* const* d_in, const int* in_sizes, int n_in,
                              void* d_out, int out_size, void* d_ws, size_t ws_size,
                              hipStream_t stream) {
    const float* x     = (const float*)d_in[0];
    const float* aw    = (const float*)d_in[1];
    const float* ab    = (const float*)d_in[2];
    const float* gamma = (const float*)d_in[3];
    const float* beta  = (const float*)d_in[4];
    const float* gw0   = (const float*)d_in[5];
    const float* gb0   = (const float*)d_in[6];
    const float* gw1   = (const float*)d_in[7];
    const float* gb1   = (const float*)d_in[8];
    const float* alpha = (const float*)d_in[9];
    float* out = (float*)d_out;
    float* ws  = (float*)d_ws;

    // ws layout (floats):
    //   [gate_raw 401408 | attn_raw/gate_t 401408 | bn_sum 256 | bn_sumsq 256 |
    //    attn 401408 | scale 256 | shift 256]
    float* gate_raw = ws;
    float* attn_raw = ws + 401408;
    float* gate_t   = attn_raw;             // alias (timeline-disjoint)
    float* bn_sum   = ws + 802816;
    float* bn_sumsq = ws + 803072;
    float* attn     = ws + 803328;
    float* scale    = ws + 1204736;
    float* shift    = ws + 1204992;

    // zero all atomic-accumulated regions in one memset (contiguous prefix)
    hipMemsetAsync(ws, 0, (size_t)(401408 + 401408 + 512) * sizeof(float), stream);

    k1_attn <<<dim3(1792),  dim3(256), 0, stream>>>(x, aw, attn_raw);
    k1b_act <<<dim3(1568),  dim3(256), 0, stream>>>(attn_raw, ab, attn);
    k2_stats<<<dim3(8192),  dim3(256), 0, stream>>>(x, attn, bn_sum, bn_sumsq);
    k3_final<<<dim3(1),     dim3(256), 0, stream>>>(bn_sum, bn_sumsq, gamma, beta, scale, shift);
    k4_gate <<<dim3(1792),  dim3(256), 0, stream>>>(x, attn, scale, shift, gw0, gw1, gate_raw);
    k4b_tanh<<<dim3(1568),  dim3(256), 0, stream>>>(gate_raw, gb0, gb1, gate_t);
    k5_fuse <<<dim3(13312), dim3(256), 0, stream>>>(x, attn, scale, shift, gate_t, alpha, out);
}